// Round 9
// baseline (203.173 us; speedup 1.0000x reference)
//
#include <hip/hip_runtime.h>
#include <math.h>

// ---------- types / helpers ----------
typedef __attribute__((ext_vector_type(8))) short short8;
typedef __attribute__((ext_vector_type(4))) float f32x4;

__device__ __forceinline__ unsigned short f2bf(float f) {
  unsigned u = __float_as_uint(f);
  unsigned r = (u + 0x7FFFu + ((u >> 16) & 1u)) >> 16;
  return (unsigned short)r;
}

__device__ __forceinline__ void gload_lds16(const void* gsrc, void* ldst) {
  __builtin_amdgcn_global_load_lds(
      (__attribute__((address_space(1))) void*)(void*)(size_t)(const char*)gsrc,
      (__attribute__((address_space(3))) void*)ldst, 16, 0, 0);
}

// ---------- prep: bf16 converts (embed, post_w^T) ----------
__global__ __launch_bounds__(256) void prep_convert_kernel(
    const float* __restrict__ embed, const float* __restrict__ post_w,
    unsigned short* __restrict__ embedbf, unsigned short* __restrict__ pwtbf) {
  int id = blockIdx.x * 256 + threadIdx.x;
  if (id < 1048576) {
    embedbf[id] = f2bf(embed[id]);
  } else {
    int i = id - 1048576;   // pwt[j][d] = post_w[d][j]
    int j = i >> 10, dd = i & 1023;
    pwtbf[i] = f2bf(post_w[dd * 256 + j]);
  }
}

// ---------- wtf[c][d] = pre_w[d][c]  (64x64 LDS tile transpose) ----------
__global__ __launch_bounds__(256) void wtrans_kernel(
    const float* __restrict__ pre_w, float* __restrict__ wtf) {
  __shared__ float tile[64][65];
  const int bc = blockIdx.x;  // c-tile 0..15
  const int bd = blockIdx.y;  // d-tile 0..3
  const int t = threadIdx.x;
  const int col = t & 63, rr = t >> 6;
#pragma unroll
  for (int i = 0; i < 16; ++i) {
    int row = rr + i * 4;  // d within tile
    tile[row][col] = pre_w[(size_t)(bd * 64 + row) * 1024 + bc * 64 + col];
  }
  __syncthreads();
#pragma unroll
  for (int i = 0; i < 16; ++i) {
    int row = rr + i * 4;  // c within tile
    wtf[(size_t)(bc * 64 + row) * 256 + bd * 64 + col] = tile[col][row];
  }
}

// ---------- e_sq[k], q[k]=pre_b.e_k, c0[k] ----------
__global__ __launch_bounds__(256) void esq_kernel(
    const float* __restrict__ embed, const float* __restrict__ pre_b,
    float* __restrict__ e_sq, float* __restrict__ qv, float* __restrict__ c0) {
  int t = threadIdx.x, l = t & 63, w = t >> 6;
  int k = blockIdx.x * 4 + w;
  const float* er = embed + (size_t)k * 1024;
  float s1 = 0.f, s2 = 0.f;
#pragma unroll
  for (int j = 0; j < 16; ++j) {
    float e = er[l + 64 * j];
    s1 += e * e;
    s2 += pre_b[l + 64 * j] * e;
  }
  for (int m = 32; m; m >>= 1) { s1 += __shfl_xor(s1, m); s2 += __shfl_xor(s2, m); }
  if (l == 0) { e_sq[k] = s1; qv[k] = s2; c0[k] = s1 - 2.0f * s2 - 1024.0f; }
}

// ---------- P[k][d] = sum_c embed[k,c] * wtf[c,d]  (coalesced, fp64 accum) ----------
__global__ __launch_bounds__(512) void pgemm_kernel(
    const float* __restrict__ embed, const float* __restrict__ wtf,
    float* __restrict__ prow, unsigned short* __restrict__ prowbf) {
  __shared__ float Es[4096];
  __shared__ double Ps[1024];
  const int t = threadIdx.x;
  const int k0 = blockIdx.x * 4;
  *(float4*)(Es + t * 8) = *(const float4*)(embed + (size_t)k0 * 1024 + t * 8);
  *(float4*)(Es + t * 8 + 4) = *(const float4*)(embed + (size_t)k0 * 1024 + t * 8 + 4);
  __syncthreads();
  const int half = t >> 8, tl = t & 255;
  const int cbase = half * 512;
  double a0 = 0, a1 = 0, a2 = 0, a3 = 0;
  const float* wp = wtf + (size_t)cbase * 256 + tl;
#pragma unroll 4
  for (int cc = 0; cc < 512; ++cc) {
    double wv = (double)wp[(size_t)cc * 256];
    int c = cbase + cc;
    a0 += wv * (double)Es[c];
    a1 += wv * (double)Es[1024 + c];
    a2 += wv * (double)Es[2048 + c];
    a3 += wv * (double)Es[3072 + c];
  }
  if (half == 0) {
    Ps[tl] = a0; Ps[256 + tl] = a1; Ps[512 + tl] = a2; Ps[768 + tl] = a3;
  }
  __syncthreads();
  if (half == 1) {
    float p0 = (float)(a0 + Ps[tl]);
    float p1 = (float)(a1 + Ps[256 + tl]);
    float p2 = (float)(a2 + Ps[512 + tl]);
    float p3 = (float)(a3 + Ps[768 + tl]);
    prow[(size_t)k0 * 256 + tl] = p0;
    prow[(size_t)(k0 + 1) * 256 + tl] = p1;
    prow[(size_t)(k0 + 2) * 256 + tl] = p2;
    prow[(size_t)(k0 + 3) * 256 + tl] = p3;
    prowbf[(size_t)k0 * 256 + tl] = f2bf(p0);
    prowbf[(size_t)(k0 + 1) * 256 + tl] = f2bf(p1);
    prowbf[(size_t)(k0 + 2) * 256 + tl] = f2bf(p2);
    prowbf[(size_t)(k0 + 3) * 256 + tl] = f2bf(p3);
  }
}

// ---------- Q[a][d] = sum_c pre_w[a,c]*wtf[c,d] (bf16 out); wbv = {2*W.b, ||b||^2} ----------
__global__ __launch_bounds__(512) void qmat_kernel(
    const float* __restrict__ pre_w, const float* __restrict__ wtf,
    const float* __restrict__ pre_b,
    unsigned short* __restrict__ qbf, float* __restrict__ wbv) {
  __shared__ float As[4096];
  __shared__ float Ps[1024];
  const int t = threadIdx.x;
  const int half = t >> 8, tl = t & 255;
  if (blockIdx.x < 64) {
    const int a0i = blockIdx.x * 4;
    *(float4*)(As + t * 8) = *(const float4*)(pre_w + (size_t)a0i * 1024 + t * 8);
    *(float4*)(As + t * 8 + 4) = *(const float4*)(pre_w + (size_t)a0i * 1024 + t * 8 + 4);
    __syncthreads();
    const int cbase = half * 512;
    float a0 = 0.f, a1 = 0.f, a2 = 0.f, a3 = 0.f;
    const float* wp = wtf + (size_t)cbase * 256 + tl;
#pragma unroll 4
    for (int cc = 0; cc < 512; ++cc) {
      float wv = wp[(size_t)cc * 256];
      int c = cbase + cc;
      a0 += wv * As[c];
      a1 += wv * As[1024 + c];
      a2 += wv * As[2048 + c];
      a3 += wv * As[3072 + c];
    }
    if (half == 0) {
      Ps[tl] = a0; Ps[256 + tl] = a1; Ps[512 + tl] = a2; Ps[768 + tl] = a3;
    }
    __syncthreads();
    if (half == 1) {
      qbf[(size_t)a0i * 256 + tl] = f2bf(a0 + Ps[tl]);
      qbf[(size_t)(a0i + 1) * 256 + tl] = f2bf(a1 + Ps[256 + tl]);
      qbf[(size_t)(a0i + 2) * 256 + tl] = f2bf(a2 + Ps[512 + tl]);
      qbf[(size_t)(a0i + 3) * 256 + tl] = f2bf(a3 + Ps[768 + tl]);
    }
  } else {
    float s = 0.f;
    const float* wp = wtf + (size_t)(half * 512) * 256 + tl;
#pragma unroll 8
    for (int cc = 0; cc < 512; ++cc) s += wp[(size_t)cc * 256] * pre_b[half * 512 + cc];
    Ps[t] = s;
    float sb = 0.f;
    if (t < 256) {
      float4 bv = *(const float4*)(pre_b + t * 4);
      sb = bv.x * bv.x + bv.y * bv.y + bv.z * bv.z + bv.w * bv.w;
    }
    for (int m = 32; m; m >>= 1) sb += __shfl_xor(sb, m);
    if ((t & 63) == 0 && t < 256) As[t >> 6] = sb;
    __syncthreads();
    if (half == 0) wbv[tl] = 2.f * (Ps[tl] + Ps[256 + tl]);
    if (t == 0) wbv[256] = As[0] + As[1] + As[2] + As[3];
  }
}

// ---------- LN + GELU: g (f32) and g (bf16) ----------
__global__ __launch_bounds__(256) void lngelu_kernel(
    const float* __restrict__ x, const float* __restrict__ gamma,
    const float* __restrict__ beta, float* __restrict__ g,
    unsigned short* __restrict__ gbf) {
  int t = threadIdx.x, l = t & 63, w = t >> 6;
  int r = blockIdx.x * 4 + w;
  const float4 xv = *(const float4*)(x + (size_t)r * 256 + l * 4);
  float s = xv.x + xv.y + xv.z + xv.w;
  for (int m = 32; m; m >>= 1) s += __shfl_xor(s, m);
  const float mu = s * (1.0f / 256.0f);
  float dx = xv.x - mu, dy = xv.y - mu, dz = xv.z - mu, dw = xv.w - mu;
  float vs = dx * dx + dy * dy + dz * dz + dw * dw;
  for (int m = 32; m; m >>= 1) vs += __shfl_xor(vs, m);
  const float rstd = rsqrtf(vs * (1.0f / 256.0f) + 1e-5f);
  float4 gm = *(const float4*)(gamma + l * 4);
  float4 bt = *(const float4*)(beta + l * 4);
  float v0 = dx * rstd * gm.x + bt.x;
  float v1 = dy * rstd * gm.y + bt.y;
  float v2 = dz * rstd * gm.z + bt.z;
  float v3 = dw * rstd * gm.w + bt.w;
  const float is2 = 0.70710678118654752f;
  float4 o;
  o.x = 0.5f * v0 * (1.0f + erff(v0 * is2));
  o.y = 0.5f * v1 * (1.0f + erff(v1 * is2));
  o.z = 0.5f * v2 * (1.0f + erff(v2 * is2));
  o.w = 0.5f * v3 * (1.0f + erff(v3 * is2));
  *(float4*)(g + (size_t)r * 256 + l * 4) = o;
  ushort4 u;
  u.x = f2bf(o.x); u.y = f2bf(o.y); u.z = f2bf(o.z); u.w = f2bf(o.w);
  *(ushort4*)(gbf + (size_t)r * 256 + l * 4) = u;
}

// Swizzled stage: linear LDS dest (gload_lds requirement); global SOURCE slot
// XOR-permuted; read side applies the same XOR. Bank-conflict-free ds_read.
__device__ __forceinline__ void stage_tile256(
    int t, const unsigned short* __restrict__ Asrc, size_t a_row_stride,
    const unsigned short* __restrict__ Bsrc, size_t b_row_stride, int k0,
    unsigned short* Ab, unsigned short* Bb) {
#pragma unroll
  for (int i = 0; i < 4; ++i) {
    int ca = t + 256 * i;
    int r = ca >> 3;
    int sp = (ca & 7) ^ (r & 7);
    gload_lds16(Asrc + (size_t)r * a_row_stride + k0 + sp * 8, (char*)Ab + ca * 16);
    gload_lds16(Bsrc + (size_t)r * b_row_stride + k0 + sp * 8, (char*)Bb + ca * 16);
  }
}

// Proven schedule (passed full harness): issue stage(next tile) BEFORE
// compute(cur); one __syncthreads (full drain) per K-step.
#define SAFE_LOOP_BODY(cur)                                                    \
    const unsigned short* Ab = &lds[cur][0];                                   \
    const unsigned short* Bb = &lds[cur][8192];                                \
    _Pragma("unroll")                                                          \
    for (int ks = 0; ks < 2; ++ks) {                                           \
      const int sp = ((ks << 2) + (l >> 4)) ^ (l & 7);                         \
      short8 af[4], bq[4];                                                     \
      _Pragma("unroll")                                                        \
      for (int mi = 0; mi < 4; ++mi)                                           \
        af[mi] = *(const short8*)(Ab + (wm + mi * 16 + (l & 15)) * 64 + sp * 8); \
      _Pragma("unroll")                                                        \
      for (int ni = 0; ni < 4; ++ni)                                           \
        bq[ni] = *(const short8*)(Bb + (wn + ni * 16 + (l & 15)) * 64 + sp * 8); \
      _Pragma("unroll")                                                        \
      for (int mi = 0; mi < 4; ++mi)                                           \
        _Pragma("unroll")                                                      \
        for (int ni = 0; ni < 4; ++ni)                                         \
          acc[mi][ni] = __builtin_amdgcn_mfma_f32_16x16x32_bf16(af[mi], bq[ni], acc[mi][ni], 0, 0, 0); \
    }

// ---------- G1: scores + per-row-segment mins. M=32768 N=1024 K=256 ----------
// Grid (bm=256 on x, bn=8 on y): XCD = linear_id % 8 = bm % 8, so all 8
// bn-blocks of a bm share one XCD's L2 (A-tile fetched once per XCD).
__global__ __launch_bounds__(256) void g1_kernel(
    const unsigned short* __restrict__ gbf,     // [32768][256]
    const unsigned short* __restrict__ prowbf,  // [1024][256]
    const float* __restrict__ c0,
    unsigned short* __restrict__ scores,        // [32768][1024]
    unsigned short* __restrict__ minbuf) {      // [32768][16] seg mins (bf16)
  __shared__ unsigned short lds[2][16384];
  const int t = threadIdx.x;
  const int bm = blockIdx.x;   // 0..255
  const int bn = blockIdx.y;   // 0..7
  const int m0 = bm * 128;
  const unsigned short* Bsrc = prowbf + bn * 128 * 256;
  f32x4 acc[4][4] = {};
  const int w = t >> 6, l = t & 63;
  const int wm = (w >> 1) * 64, wn = (w & 1) * 64;

  stage_tile256(t, gbf + (size_t)m0 * 256, 256, Bsrc, 256, 0, &lds[0][0], &lds[0][8192]);
  __syncthreads();
  for (int kt = 0; kt < 4; ++kt) {
    const int cur = kt & 1;
    if (kt < 3)
      stage_tile256(t, gbf + (size_t)m0 * 256, 256, Bsrc, 256, (kt + 1) * 64,
                    &lds[cur ^ 1][0], &lds[cur ^ 1][8192]);
    SAFE_LOOP_BODY(cur)
    __syncthreads();
  }
  const int lrow = (l >> 4) * 4;
  const int lcol = l & 15;
  const int n0 = bn * 128;
  const int seg = bn * 2 + (wn >> 6);  // 64-col segment index 0..15
#pragma unroll
  for (int mi = 0; mi < 4; ++mi) {
#pragma unroll
    for (int r = 0; r < 4; ++r) {
      const int grow = m0 + wm + mi * 16 + lrow + r;
      float mn4 = 1e30f;
#pragma unroll
      for (int ni = 0; ni < 4; ++ni) {
        int gcol = n0 + wn + ni * 16 + lcol;
        unsigned short u = f2bf(c0[gcol] - 2.0f * acc[mi][ni][r]);
        scores[(size_t)grow * 1024 + gcol] = u;
        mn4 = fminf(mn4, __uint_as_float((unsigned)u << 16));
      }
      mn4 = fminf(mn4, __shfl_xor(mn4, 1));
      mn4 = fminf(mn4, __shfl_xor(mn4, 2));
      mn4 = fminf(mn4, __shfl_xor(mn4, 4));
      mn4 = fminf(mn4, __shfl_xor(mn4, 8));
      if (lcol == 0)
        minbuf[(size_t)grow * 16 + seg] = (unsigned short)(__float_as_uint(mn4) >> 16);
    }
  }
}

// ---------- ZQ: z_sq via Q. gQ = G@Q, z_sq=rowsum(gQ*G)+2g.wb+bsq ----------
__global__ __launch_bounds__(256) void zq_kernel(
    const unsigned short* __restrict__ gbf, const unsigned short* __restrict__ qbf,
    const float* __restrict__ g, const float* __restrict__ wbv,
    float* __restrict__ z_sq) {
  __shared__ unsigned short lds[2][16384];
  const int t = threadIdx.x;
  const int bm = blockIdx.x;  // 0..255
  const int bn = blockIdx.y;  // 0..1
  const int m0 = bm * 128;
  const unsigned short* Bsrc = qbf + bn * 128 * 256;
  f32x4 acc[4][4] = {};
  const int w = t >> 6, l = t & 63;
  const int wm = (w >> 1) * 64, wn = (w & 1) * 64;

  stage_tile256(t, gbf + (size_t)m0 * 256, 256, Bsrc, 256, 0, &lds[0][0], &lds[0][8192]);
  __syncthreads();
  for (int kt = 0; kt < 4; ++kt) {
    const int cur = kt & 1;
    if (kt < 3)
      stage_tile256(t, gbf + (size_t)m0 * 256, 256, Bsrc, 256, (kt + 1) * 64,
                    &lds[cur ^ 1][0], &lds[cur ^ 1][8192]);
    SAFE_LOOP_BODY(cur)
    __syncthreads();
  }
  const int lrow = (l >> 4) * 4;
  const int lcol = l & 15;
  const float bsq = wbv[256];
#pragma unroll
  for (int mi = 0; mi < 4; ++mi)
#pragma unroll
    for (int r = 0; r < 4; ++r) {
      int grow = m0 + wm + mi * 16 + lrow + r;
      float v = 0.f;
#pragma unroll
      for (int ni = 0; ni < 4; ++ni) {
        int gcol = bn * 128 + wn + ni * 16 + lcol;
        float gv = g[(size_t)grow * 256 + gcol];
        v += gv * (acc[mi][ni][r] + wbv[gcol]);
      }
      v += __shfl_xor(v, 1); v += __shfl_xor(v, 2);
      v += __shfl_xor(v, 4); v += __shfl_xor(v, 8);
      if (lcol == 0)
        atomicAdd(&z_sq[grow], v + ((bn == 0 && wn == 0) ? bsq : 0.f));
    }
}

// ---------- segment-skip min + margin candidates + exact fp32 refine + loss ----------
// Candidate set provably identical to full-scan: any col with score<=T lies in
// a segment whose min<=T, and those segments are all scanned.
__global__ __launch_bounds__(256) void refine_kernel(
    const unsigned short* __restrict__ scores, const unsigned short* __restrict__ minbuf,
    const float* __restrict__ g, const float* __restrict__ prow,
    const float* __restrict__ e_sq, const float* __restrict__ qv,
    const float* __restrict__ z_sq,
    int* __restrict__ idxout, float* __restrict__ fidx,
    float* __restrict__ loss_slots) {
  const int t = threadIdx.x, l = t & 63, w = t >> 6;
  const int r = blockIdx.x * 4 + w;
  const unsigned short* srow = scores + (size_t)r * 1024;
  float segmin[16];
  {
    uint4 m0v = *(const uint4*)(minbuf + (size_t)r * 16);
    uint4 m1v = *(const uint4*)(minbuf + (size_t)r * 16 + 8);
    unsigned mm[8] = {m0v.x, m0v.y, m0v.z, m0v.w, m1v.x, m1v.y, m1v.z, m1v.w};
#pragma unroll
    for (int j = 0; j < 8; ++j) {
      segmin[2 * j] = __uint_as_float(mm[j] << 16);
      segmin[2 * j + 1] = __uint_as_float(mm[j] & 0xFFFF0000u);
    }
  }
  float mn = segmin[0];
#pragma unroll
  for (int j = 1; j < 16; ++j) mn = fminf(mn, segmin[j]);
  const float T = mn + 8.0f;

  float gv[4];
  const float* gr = g + (size_t)r * 256;
#pragma unroll
  for (int j = 0; j < 4; ++j) gv[j] = gr[l + 64 * j];

  float bestd = 1e30f; int bestk = 0x7fffffff;
#pragma unroll 1
  for (int s = 0; s < 16; ++s) {
    if (segmin[s] > T) continue;  // wave-uniform branch
    float val = __uint_as_float((unsigned)srow[s * 64 + l] << 16);
    unsigned long long msk = __ballot(val <= T);
    while (msk) {
      int src = __ffsll(msk) - 1;
      msk &= msk - 1;
      int k = s * 64 + src;
      const float* pr = prow + (size_t)k * 256;
      float p = 0.f;
#pragma unroll
      for (int jj = 0; jj < 4; ++jj) p += gv[jj] * pr[l + 64 * jj];
      for (int m = 32; m; m >>= 1) p += __shfl_xor(p, m);
      float d = e_sq[k] - 2.0f * (p + qv[k]);
      if (d < bestd || (d == bestd && k < bestk)) { bestd = d; bestk = k; }
    }
  }
  if (l == 0) {
    idxout[r] = bestk;
    fidx[r] = (float)bestk;
    atomicAdd(&loss_slots[r & 2047], z_sq[r] + bestd);
  }
}

// ---------- G2: quantized = embed[idx] @ post_w + post_b. M=32768 N=256 K=1024 ----------
__global__ __launch_bounds__(256) void g2_kernel(
    const unsigned short* __restrict__ embedbf,  // [1024][1024]
    const unsigned short* __restrict__ pwtbf,    // [256][1024]
    const int* __restrict__ idx, const float* __restrict__ post_b,
    float* __restrict__ out) {
  __shared__ unsigned short lds[2][16384];
  const int t = threadIdx.x;
  const int bm = blockIdx.x;  // 0..255
  const int bn = blockIdx.y;  // 0..1
  const int m0 = bm * 128;
  const int w = t >> 6, l = t & 63;
  const int wm = (w >> 1) * 64, wn = (w & 1) * 64;
  const int rbase = t >> 3;
  const int sp_st = (t & 7) ^ (rbase & 7);
  size_t arow[4];
#pragma unroll
  for (int i = 0; i < 4; ++i)
    arow[i] = (size_t)idx[m0 + rbase + 32 * i] * 1024;
  f32x4 acc[4][4] = {};
  auto stage = [&](int buf, int kt) {
    const int k0 = kt * 64;
    unsigned short* Ab = &lds[buf][0];
    unsigned short* Bb = &lds[buf][8192];
#pragma unroll
    for (int i = 0; i < 4; ++i) {
      int ca = t + 256 * i;
      int rr = rbase + 32 * i;
      gload_lds16(embedbf + arow[i] + k0 + sp_st * 8, (char*)Ab + ca * 16);
      gload_lds16(pwtbf + (size_t)(bn * 128 + rr) * 1024 + k0 + sp_st * 8,
                  (char*)Bb + ca * 16);
    }
  };
  stage(0, 0);
  __syncthreads();
  for (int kt = 0; kt < 16; ++kt) {
    const int cur = kt & 1;
    if (kt < 15) stage(cur ^ 1, kt + 1);
    SAFE_LOOP_BODY(cur)
    __syncthreads();
  }
  const int lrow = (l >> 4) * 4, lcol = l & 15;
#pragma unroll
  for (int mi = 0; mi < 4; ++mi)
#pragma unroll
    for (int ni = 0; ni < 4; ++ni) {
      int gcol = bn * 128 + wn + ni * 16 + lcol;
      float pb = post_b[gcol];
#pragma unroll
      for (int r = 0; r < 4; ++r) {
        int grow = m0 + wm + mi * 16 + lrow + r;
        out[(size_t)grow * 256 + gcol] = acc[mi][ni][r] + pb;
      }
    }
}

// ---------- loss finalize ----------
__global__ __launch_bounds__(256) void loss_final_kernel(
    const float* __restrict__ slots, float* __restrict__ out_loss) {
  float s = 0.f;
  for (int i = threadIdx.x; i < 2048; i += 256) s += slots[i];
  for (int m = 32; m; m >>= 1) s += __shfl_xor(s, m);
  __shared__ float ws_[4];
  if ((threadIdx.x & 63) == 0) ws_[threadIdx.x >> 6] = s;
  __syncthreads();
  if (threadIdx.x == 0)
    out_loss[0] = 1.25f * (ws_[0] + ws_[1] + ws_[2] + ws_[3]) / 33554432.0f;
}

extern "C" void kernel_launch(void* const* d_in, const int* in_sizes, int n_in,
                              void* d_out, int out_size, void* d_ws, size_t ws_size,
                              hipStream_t stream) {
  const float* x = (const float*)d_in[0];
  const float* ln_g = (const float*)d_in[1];
  const float* ln_b = (const float*)d_in[2];
  const float* pre_w = (const float*)d_in[3];
  const float* pre_b = (const float*)d_in[4];
  const float* embed = (const float*)d_in[5];
  const float* post_w = (const float*)d_in[6];
  const float* post_b = (const float*)d_in[7];
  float* out_q = (float*)d_out;
  float* out_idx = out_q + 8388608;
  float* out_loss = out_q + 8421376;

  char* ws = (char*)d_ws;
  size_t off = 0;
  auto alloc = [&](size_t n) { char* p = ws + off; off += (n + 255) & ~(size_t)255; return p; };
  float* g_f32 = (float*)alloc(33554432);
  unsigned short* g_bf = (unsigned short*)alloc(16777216);
  unsigned short* scores = (unsigned short*)alloc(67108864);
  unsigned short* minbuf = (unsigned short*)alloc(1048576);
  float* prow = (float*)alloc(1048576);
  unsigned short* prowbf = (unsigned short*)alloc(524288);
  unsigned short* pwtbf = (unsigned short*)alloc(524288);
  unsigned short* embedbf = (unsigned short*)alloc(2097152);
  unsigned short* qbf = (unsigned short*)alloc(131072);
  float* wtf = (float*)alloc(1048576);
  float* wbv = (float*)alloc(2048);
  float* e_sq = (float*)alloc(4096);
  float* qv = (float*)alloc(4096);
  float* c0 = (float*)alloc(4096);
  float* z_sq = (float*)alloc(131072);
  int* idxw = (int*)alloc(131072);
  float* slots = (float*)alloc(8192);
  (void)ws_size; (void)in_sizes; (void)n_in; (void)out_size;

  hipMemsetAsync(z_sq, 0, 131072, stream);
  hipMemsetAsync(slots, 0, 8192, stream);

  prep_convert_kernel<<<5120, 256, 0, stream>>>(embed, post_w, embedbf, pwtbf);
  dim3 wtg(16, 4);
  wtrans_kernel<<<wtg, 256, 0, stream>>>(pre_w, wtf);
  esq_kernel<<<256, 256, 0, stream>>>(embed, pre_b, e_sq, qv, c0);
  pgemm_kernel<<<256, 512, 0, stream>>>(embed, wtf, prow, prowbf);
  qmat_kernel<<<65, 512, 0, stream>>>(pre_w, wtf, pre_b, qbf, wbv);
  lngelu_kernel<<<8192, 256, 0, stream>>>(x, ln_g, ln_b, g_f32, g_bf);
  dim3 g1grid(256, 8);
  g1_kernel<<<g1grid, 256, 0, stream>>>(g_bf, prowbf, c0, scores, minbuf);
  dim3 zqgrid(256, 2);
  zq_kernel<<<zqgrid, 256, 0, stream>>>(g_bf, qbf, g_f32, wbv, z_sq);
  refine_kernel<<<8192, 256, 0, stream>>>(scores, minbuf, g_f32, prow, e_sq, qv, z_sq, idxw, out_idx, slots);
  dim3 g2grid(256, 2);
  g2_kernel<<<g2grid, 256, 0, stream>>>(embedbf, pwtbf, idxw, post_b, out_q);
  loss_final_kernel<<<1, 256, 0, stream>>>(slots, out_loss);
}